// Round 6
// baseline (218.905 us; speedup 1.0000x reference)
//
#include <hip/hip_runtime.h>
#include <stdint.h>
#include <math.h>

// ---------------------------------------------------------------------------
// IID segmentation loss on MI355X.  Round 6.
//
// C[(n,dx)][(o,dy)] = sum_{b,y,x} xo[b,n,y,x+dx-7] * xt[b,o,y+7-dy,x]
// R5 post-mortem: kw xc-imbalance at barriers regressed K1; stalls are the
// per-y vmcnt(0) barrier drain + DMA/prefetch vmcnt interference + 64-bit
// address VALU.  R6: NO LDS, NO DMA, NO BARRIERS in the K-loop.
//   - A,B frags straight from padded bf16 global (L1/L2/L3-resident),
//     SADDR form: uniform class-slab SGPR bases (readfirstlane) + one
//     32-bit voffset per side; xc = 64B immediate in a fully-unrolled
//     7-step period; explicit distance-1 double buffer.
//   - 256 blocks x 512 thr; kw = y-parity split (perfectly balanced,
//     7 y's each); halves merged in a 20KB-LDS epilogue; partials = 256.
// ---------------------------------------------------------------------------

#define PADV 7
#define TS 15
#define KCLS 10
#define HH 224
#define WW 224
#define MD 160
#define NCELL (MD*MD)
#define NBLK 256
#define BSTRIDE 232
#define BPH 240
#define ADW 120
#define LEPS 1e-16

typedef __attribute__((ext_vector_type(4))) float f32x4;
typedef __attribute__((ext_vector_type(8))) short bf16x8;

__device__ __forceinline__ unsigned short f2bf(float f) {
  union { float f; uint32_t u; } v; v.f = f;
  return (unsigned short)((v.u + 0x7FFFu + ((v.u >> 16) & 1u)) >> 16);
}

struct U5 { uint32_t u[5]; };

// ---------------------------------------------------- prep: apad + bpad
#define BPREP_BLOCKS 4350   // 160*240*29 threads
#define APREP_BLOCKS 4200   // 160*224*30 threads
__global__ __launch_bounds__(256)
void prep(const float* __restrict__ xo, const float* __restrict__ xt,
          unsigned short* __restrict__ bp, uint32_t* __restrict__ ap) {
  if (blockIdx.x < BPREP_BLOCKS) {
    const int idx   = blockIdx.x * 256 + threadIdx.x;
    const int rowid = idx / 29;
    const int chunk = idx - rowid * 29;
    const int x0    = chunk * 8;
    const int yy    = rowid % BPH;
    const int cls   = rowid / BPH;
    const int row   = yy - PADV;
    union { unsigned short h[8]; uint4 v; } out;
    if (row >= 0 && row < HH && x0 < WW) {
      const float* src = xt + ((size_t)cls * HH + row) * WW + x0;
#pragma unroll
      for (int j = 0; j < 8; ++j) out.h[j] = f2bf(src[j]);
    } else {
      out.v = make_uint4(0u, 0u, 0u, 0u);
    }
    *(uint4*)(bp + (size_t)rowid * BSTRIDE + x0) = out.v;
  } else {
    const int idx   = (blockIdx.x - BPREP_BLOCKS) * 256 + threadIdx.x;
    const int rowid = idx / 30;               // cls*224 + y
    const int wg    = idx - rowid * 30;
    const float* src = xo + (size_t)rowid * WW;
    float e[8];
#pragma unroll
    for (int j = 0; j < 8; ++j) {
      const int x = 8 * wg + j - PADV;
      e[j] = (x >= 0 && x < WW) ? src[x] : 0.f;
    }
    union { uint32_t u[4]; uint4 v; } o;
#pragma unroll
    for (int k = 0; k < 4; ++k)
      o.u[k] = (uint32_t)f2bf(e[2 * k]) | ((uint32_t)f2bf(e[2 * k + 1]) << 16);
    *(uint4*)(ap + (size_t)rowid * ADW + 4 * wg) = o.v;
  }
}

// ---------------------------------------------------------------- K1: GEMM
__global__ __launch_bounds__(512, 2)
void corr_gemm(const uint32_t* __restrict__ apad,
               const unsigned short* __restrict__ bpad,
               float* __restrict__ partials) {
  __shared__ __align__(16) float ex[5120];   // epilogue merge scratch (20 KB)

  const int tid  = threadIdx.x;
  const int bid  = blockIdx.x;
  const int b    = bid >> 4;                 // 16 batches
  const int y0   = (bid & 15) * 14;          // 16 strips of 14 rows

  const int lane = tid & 63;
  const int wv   = tid >> 6;                 // 0..7
  const int wm   = wv & 1;
  const int wn   = (wv >> 1) & 1;
  const int kw   = wv >> 2;                  // y-parity K-split
  const int quad = lane >> 4;
  const int l15  = lane & 15;
  const int shA  = (l15 & 1) << 4;

  // wave-uniform class-slab bases (force SGPR via readfirstlane)
  const int clsA0 = __builtin_amdgcn_readfirstlane(b * KCLS + wm * 5);
  const int clsB0 = __builtin_amdgcn_readfirstlane(b * KCLS + wn * 5);
  const char* sA[5];
  const char* sB[5];
#pragma unroll
  for (int mi = 0; mi < 5; ++mi)
    sA[mi] = (const char*)apad + (size_t)(clsA0 + mi) * HH * (ADW * 4);
#pragma unroll
  for (int ni = 0; ni < 5; ++ni)   // -4096 bias so voffB stays non-negative
    sB[ni] = (const char*)bpad + (size_t)(clsB0 + ni) * BPH * (BSTRIDE * 2) - 4096;

  // per-lane 32-bit voffsets
  unsigned voffA = (unsigned)((y0 + kw) * (ADW * 4) + quad * 16 + (l15 >> 1) * 4);
  unsigned voffB = (unsigned)((y0 + kw + 14 - l15) * (BSTRIDE * 2) + quad * 16 + 4096);

  f32x4 acc[5][5];
#pragma unroll
  for (int i = 0; i < 5; ++i)
#pragma unroll
    for (int j = 0; j < 5; ++j) acc[i][j] = (f32x4){0.f, 0.f, 0.f, 0.f};

  U5   curA[5], nxtA[5];
  uint4 curB[5], nxtB[5];

  auto fetch = [&](int imm, U5 (&A)[5], uint4 (&B)[5]) {
#pragma unroll
    for (int mi = 0; mi < 5; ++mi) {
      uint4 t;
      __builtin_memcpy(&t, sA[mi] + voffA + imm, 16);
      A[mi].u[0] = t.x; A[mi].u[1] = t.y; A[mi].u[2] = t.z; A[mi].u[3] = t.w;
      uint32_t e;
      __builtin_memcpy(&e, sA[mi] + voffA + imm + 16, 4);
      A[mi].u[4] = e;
    }
#pragma unroll
    for (int ni = 0; ni < 5; ++ni)
      __builtin_memcpy(&B[ni], sB[ni] + voffB + imm, 16);
  };

  auto compute = [&](U5 (&A)[5], uint4 (&B)[5]) {
    bf16x8 afrag[5], bfrag[5];
#pragma unroll
    for (int mi = 0; mi < 5; ++mi) {
      union { uint32_t u[4]; bf16x8 v; } cv;
      cv.u[0] = __builtin_amdgcn_alignbit(A[mi].u[1], A[mi].u[0], shA);
      cv.u[1] = __builtin_amdgcn_alignbit(A[mi].u[2], A[mi].u[1], shA);
      cv.u[2] = __builtin_amdgcn_alignbit(A[mi].u[3], A[mi].u[2], shA);
      cv.u[3] = __builtin_amdgcn_alignbit(A[mi].u[4], A[mi].u[3], shA);
      afrag[mi] = cv.v;
    }
#pragma unroll
    for (int ni = 0; ni < 5; ++ni) {
      union { uint4 q; bf16x8 v; } bv; bv.q = B[ni];
      bfrag[ni] = bv.v;
    }
#pragma unroll
    for (int mi = 0; mi < 5; ++mi)
#pragma unroll
      for (int ni = 0; ni < 5; ++ni)
        acc[mi][ni] = __builtin_amdgcn_mfma_f32_16x16x32_bf16(
            afrag[mi], bfrag[ni], acc[mi][ni], 0, 0, 0);
  };

  fetch(0, curA, curB);   // prologue: (y0+kw, xc=0)

#pragma unroll 1
  for (int iy = 0; iy < 7; ++iy) {
    fetch(64,  nxtA, nxtB);  compute(curA, curB);   // xc0
    fetch(128, curA, curB);  compute(nxtA, nxtB);   // xc1
    fetch(192, nxtA, nxtB);  compute(curA, curB);   // xc2
    fetch(256, curA, curB);  compute(nxtA, nxtB);   // xc3
    fetch(320, nxtA, nxtB);  compute(curA, curB);   // xc4
    fetch(384, curA, curB);  compute(nxtA, nxtB);   // xc5
    voffA += 2 * ADW * 4;            // y += 2
    voffB += 2 * BSTRIDE * 2;
    if (iy < 6) fetch(0, nxtA, nxtB);
    compute(curA, curB);                            // xc6 (fetched at xc5)
    if (iy < 6) {
#pragma unroll
      for (int mi = 0; mi < 5; ++mi)
#pragma unroll
        for (int r = 0; r < 5; ++r) curA[mi].u[r] = nxtA[mi].u[r];
#pragma unroll
      for (int ni = 0; ni < 5; ++ni) curB[ni] = nxtB[ni];
    }
  }

  // ---- epilogue: merge kw halves via LDS, kw0 stores ----
  const int w1 = wm * 2 + wn;
  float* outp = partials + (size_t)bid * NCELL;
#pragma unroll 1
  for (int r = 0; r < 5; ++r) {        // mi rounds
    __syncthreads();
    if (kw == 1) {
#pragma unroll
      for (int ni = 0; ni < 5; ++ni)
        *(f32x4*)(ex + ((w1 * 5 + ni) * 64 + lane) * 4) = acc[r][ni];
    }
    __syncthreads();
    if (kw == 0) {
      const int mrow = (wm * 5 + r) * 16 + quad * 4;
#pragma unroll
      for (int ni = 0; ni < 5; ++ni) {
        const f32x4 other = *(const f32x4*)(ex + ((w1 * 5 + ni) * 64 + lane) * 4);
        const int ncol = (wn * 5 + ni) * 16 + l15;
#pragma unroll
        for (int rr = 0; rr < 4; ++rr)
          outp[(size_t)(mrow + rr) * MD + ncol] = acc[r][ni][rr] + other[rr];
      }
    }
  }
}

// ------- reduce: 256 partials -> C (fp64) + per-block min + zero d_out
__global__ __launch_bounds__(256)
void reduce_all(const float* __restrict__ partials, float* __restrict__ Cout,
                float* __restrict__ mins, float* __restrict__ dout) {
  const int blk = blockIdx.x;             // 400 blocks x 64 cells
  const int t   = threadIdx.x;
  const int c   = blk * 64 + (t & 63);
  const int ps  = t >> 6;                 // 4-way split over partials
  if (blk == 0 && t == 0) dout[0] = 0.f;
  double s0 = 0.0, s1 = 0.0;
  const float* base = partials + c;
  for (int p = ps * 64; p < ps * 64 + 64; p += 2) {
    s0 += (double)base[(size_t)p * NCELL];
    s1 += (double)base[(size_t)(p + 1) * NCELL];
  }
  __shared__ double red[256];
  red[t] = s0 + s1;
  __syncthreads();
  if (t < 64) {
    const double tot = red[t] + red[t + 64] + red[t + 128] + red[t + 192];
    const float sf = (float)tot;
    Cout[c] = sf;
    const int m  = c / MD;
    const int nn = c - m * MD;
    const bool valid = ((m & 15) < TS) && ((nn & 15) < TS);
    float v = valid ? sf : 3.4e38f;
#pragma unroll
    for (int off = 32; off > 0; off >>= 1)
      v = fminf(v, __shfl_down(v, off));
    if (t == 0) mins[blk] = v;
  }
}

// ------------------- loss: per-shift fp64, inline global min (400 mins)
__global__ __launch_bounds__(128)
void loss_kernel(const float* __restrict__ Cmat, const float* __restrict__ mins,
                 float* __restrict__ dout) {
  const int s   = blockIdx.x;
  const int dy  = s / TS;
  const int dx  = s - dy * TS;
  const int tid = threadIdx.x;
  __shared__ float fm[128];
  __shared__ double q[100];
  __shared__ double sym[100];
  __shared__ double pi[10], pj[10];
  __shared__ double red[128];

  float v = 3.4e38f;
  for (int i = tid; i < 400; i += 128) v = fminf(v, mins[i]);
  fm[tid] = v;
  __syncthreads();
  for (int st = 64; st > 0; st >>= 1) {
    if (tid < st) fm[tid] = fminf(fm[tid], fm[tid + st]);
    __syncthreads();
  }
  const double minv = (double)fm[0];
  __syncthreads();

  if (tid < 100) {
    const int n = tid / 10, o = tid - (tid / 10) * 10;
    const double vv = (double)Cmat[(size_t)(n * 16 + dx) * MD + (o * 16 + dy)];
    q[tid] = vv - minv + LEPS;
  }
  __syncthreads();
  red[tid] = (tid < 100) ? q[tid] : 0.0;
  __syncthreads();
  for (int st = 64; st > 0; st >>= 1) {
    if (tid < st) red[tid] += red[tid + st];
    __syncthreads();
  }
  const double Z = red[0];
  __syncthreads();
  if (tid < 100) {
    const int n = tid / 10, o = tid - (tid / 10) * 10;
    sym[tid] = (q[n * 10 + o] + q[o * 10 + n]) * 0.5 / Z;
  }
  __syncthreads();
  if (tid < 10) {
    double a = 0.0, bsum = 0.0;
    for (int n2 = 0; n2 < 10; ++n2) {
      a    += sym[n2 * 10 + tid];
      bsum += sym[tid * 10 + n2];
    }
    pi[tid] = a;
    pj[tid] = bsum;
  }
  __syncthreads();
  double term = 0.0;
  if (tid < 100) {
    const int n = tid / 10, o = tid - (tid / 10) * 10;
    const double sp = sym[tid];
    term = -sp * (log(sp + LEPS) - log(pi[o] + LEPS) - log(pj[n] + LEPS));
  }
  red[tid] = term;
  __syncthreads();
  for (int st = 64; st > 0; st >>= 1) {
    if (tid < st) red[tid] += red[tid + st];
    __syncthreads();
  }
  if (tid == 0) atomicAdd(dout, (float)(red[0] / (double)(TS * TS)));
}

extern "C" void kernel_launch(void* const* d_in, const int* in_sizes, int n_in,
                              void* d_out, int out_size, void* d_ws, size_t ws_size,
                              hipStream_t stream) {
  const float* xo = (const float*)d_in[0];
  const float* xt = (const float*)d_in[1];
  float* ws       = (float*)d_ws;

  float* partials = ws;                                  // 256*25600 f32 = 26.2 MB
  float* Cmat     = partials + (size_t)NBLK * NCELL;     // 25600
  float* mins     = Cmat + NCELL;                        // 400 (pad 512)
  unsigned short* bpad = (unsigned short*)(mins + 512);  // 17.8 MB
  uint32_t* apad  = (uint32_t*)(bpad + (size_t)160 * BPH * BSTRIDE);  // 17.2 MB
  float* out      = (float*)d_out;

  hipLaunchKernelGGL(prep,       dim3(BPREP_BLOCKS + APREP_BLOCKS), dim3(256), 0, stream,
                     xo, xt, bpad, apad);
  hipLaunchKernelGGL(corr_gemm,  dim3(256), dim3(512), 0, stream, apad, bpad, partials);
  hipLaunchKernelGGL(reduce_all, dim3(400), dim3(256), 0, stream, partials, Cmat, mins, out);
  hipLaunchKernelGGL(loss_kernel,dim3(225), dim3(128), 0, stream, Cmat, mins, out);
}

// Round 7
// 216.582 us; speedup vs baseline: 1.0107x; 1.0107x over previous
//
#include <hip/hip_runtime.h>
#include <stdint.h>
#include <math.h>

// ---------------------------------------------------------------------------
// IID segmentation loss on MI355X.  Round 7.
//
// C[(n,dx)][(o,dy)] = sum_{b,y,x} xo[b,n,y,x+dx-7] * xt[b,o,y+7-dy,x]
// R6 failed on register spills (launch_bounds cap 128 < ~200 needed).
// R7 = R4's proven K-loop skeleton (512 blk x 256 thr, TY=7, B via async
// global_load_lds 16-slot circular window, one barrier per y) plus:
//   - ATOMIC C-update: unsafeAtomicAdd into Cmat (L2-resident, 0.1 MB).
//     Partials array ELIMINATED: no 52 MB HBM write, no reduce read-back,
//     no 52 MB of harness ws re-poison (~1 us/MB measured R2/R4/R5).
//   - Distance-2 A prefetch: 3 rotating buffers, y-bodies unrolled x3 so
//     the mod-3 buffer phase is compile-time.  launch_bounds(256,2) ->
//     VGPR cap 256 (est ~220, no spills).
//   - ws = bpad + apad + Cmat = 35.1 MB (was 87.5).
// ---------------------------------------------------------------------------

#define PADV 7
#define TS 15
#define KCLS 10
#define HH 224
#define WW 224
#define MD 160
#define NCELL (MD*MD)
#define BSTRIDE 232
#define BPH 240
#define ADW 120
#define LEPS 1e-16

typedef __attribute__((ext_vector_type(4))) float f32x4;
typedef __attribute__((ext_vector_type(8))) short bf16x8;

__device__ __forceinline__ unsigned short f2bf(float f) {
  union { float f; uint32_t u; } v; v.f = f;
  return (unsigned short)((v.u + 0x7FFFu + ((v.u >> 16) & 1u)) >> 16);
}

__device__ __forceinline__ void glds16(const unsigned short* g, unsigned short* l) {
  __builtin_amdgcn_global_load_lds(
      (const __attribute__((address_space(1))) unsigned int*)g,
      (__attribute__((address_space(3))) unsigned int*)l, 16, 0, 0);
}

struct U5 { uint32_t u[5]; };

// ---------------------------------------------------- prep: apad + bpad
#define BPREP_BLOCKS 4350   // 160*240*29 threads
#define APREP_BLOCKS 4200   // 160*224*30 threads
__global__ __launch_bounds__(256)
void prep(const float* __restrict__ xo, const float* __restrict__ xt,
          unsigned short* __restrict__ bp, uint32_t* __restrict__ ap) {
  if (blockIdx.x < BPREP_BLOCKS) {
    const int idx   = blockIdx.x * 256 + threadIdx.x;
    const int rowid = idx / 29;
    const int chunk = idx - rowid * 29;
    const int x0    = chunk * 8;
    const int yy    = rowid % BPH;
    const int cls   = rowid / BPH;
    const int row   = yy - PADV;
    union { unsigned short h[8]; uint4 v; } out;
    if (row >= 0 && row < HH && x0 < WW) {
      const float* src = xt + ((size_t)cls * HH + row) * WW + x0;
#pragma unroll
      for (int j = 0; j < 8; ++j) out.h[j] = f2bf(src[j]);
    } else {
      out.v = make_uint4(0u, 0u, 0u, 0u);
    }
    *(uint4*)(bp + (size_t)rowid * BSTRIDE + x0) = out.v;
  } else {
    const int idx   = (blockIdx.x - BPREP_BLOCKS) * 256 + threadIdx.x;
    const int rowid = idx / 30;               // cls*224 + y
    const int wg    = idx - rowid * 30;
    const float* src = xo + (size_t)rowid * WW;
    float e[8];
#pragma unroll
    for (int j = 0; j < 8; ++j) {
      const int x = 8 * wg + j - PADV;
      e[j] = (x >= 0 && x < WW) ? src[x] : 0.f;
    }
    union { uint32_t u[4]; uint4 v; } o;
#pragma unroll
    for (int k = 0; k < 4; ++k)
      o.u[k] = (uint32_t)f2bf(e[2 * k]) | ((uint32_t)f2bf(e[2 * k + 1]) << 16);
    *(uint4*)(ap + (size_t)rowid * ADW + 4 * wg) = o.v;
  }
}

// ---------------------------------------------------------------- K1: GEMM
__global__ __launch_bounds__(256, 2)
void corr_gemm(const uint32_t* __restrict__ apad,
               const unsigned short* __restrict__ bpad,
               float* __restrict__ Cmat) {
  __shared__ __align__(16) unsigned short ldsB[KCLS * 16 * BSTRIDE];  // 74240 B

  const int tid  = threadIdx.x;
  const int bid  = blockIdx.x;
  const int b    = bid >> 5;               // 16 batches
  const int y0   = (bid & 31) * 7;         // 32 strips of 7 rows

  const int lane = tid & 63;
  const int wv   = tid >> 6;               // 0..3
  const int wm   = wv & 1;
  const int wn   = wv >> 1;
  const int quad = lane >> 4;
  const int l15  = lane & 15;
  const int shA  = (l15 & 1) << 4;
  const int laneWd = quad * 4 + (l15 >> 1);

  f32x4 acc[5][5];
#pragma unroll
  for (int i = 0; i < 5; ++i)
#pragma unroll
    for (int j = 0; j < 5; ++j) acc[i][j] = (f32x4){0.f, 0.f, 0.f, 0.f};

  const unsigned short* Bb = bpad + (size_t)b * KCLS * BPH * BSTRIDE;

  // per-mi A row pointers (lane-dependent laneWd -> VGPR pointers)
  const uint32_t* PA[5];
#pragma unroll
  for (int mi = 0; mi < 5; ++mi)
    PA[mi] = apad + ((size_t)(b * KCLS + wm * 5 + mi) * HH + y0) * ADW + laneWd;

  // prologue: async DMA B rows y0-7..y0+7 (150 class-rows)
  for (int pr = wv; pr < 15 * KCLS; pr += 4) {
    const int r15  = pr / KCLS;
    const int o    = pr - r15 * KCLS;
    const int yy   = y0 + r15;
    const int slot = (y0 - PADV + r15) & 15;
    if (lane < 29)
      glds16(Bb + ((size_t)o * BPH + yy) * BSTRIDE + lane * 8,
             ldsB + (o * 16 + slot) * BSTRIDE);
  }

  U5 b0[5], b1[5], b2[5];

  auto fetchA = [&](U5 (&dst)[5], int dyi, int xc) {
#pragma unroll
    for (int mi = 0; mi < 5; ++mi) {
      const uint32_t* p = PA[mi] + dyi * ADW + xc * 16;
      uint4 t;
      __builtin_memcpy(&t, p, 16);
      dst[mi].u[0] = t.x; dst[mi].u[1] = t.y;
      dst[mi].u[2] = t.z; dst[mi].u[3] = t.w;
      dst[mi].u[4] = p[4];
    }
  };

  auto computeS = [&](U5 (&buf)[5], int slotB, int xc) {
    bf16x8 afrag[5], bfrag[5];
#pragma unroll
    for (int mi = 0; mi < 5; ++mi) {
      union { uint32_t u[4]; bf16x8 v; } cv;
      cv.u[0] = __builtin_amdgcn_alignbit(buf[mi].u[1], buf[mi].u[0], shA);
      cv.u[1] = __builtin_amdgcn_alignbit(buf[mi].u[2], buf[mi].u[1], shA);
      cv.u[2] = __builtin_amdgcn_alignbit(buf[mi].u[3], buf[mi].u[2], shA);
      cv.u[3] = __builtin_amdgcn_alignbit(buf[mi].u[4], buf[mi].u[3], shA);
      afrag[mi] = cv.v;
    }
#pragma unroll
    for (int ni = 0; ni < 5; ++ni) {
      const int to = wn * 5 + ni;
      bfrag[ni] = *(const bf16x8*)(ldsB + (to * 16 + slotB) * BSTRIDE + xc * 32 + quad * 8);
    }
#pragma unroll
    for (int mi = 0; mi < 5; ++mi)
#pragma unroll
      for (int ni = 0; ni < 5; ++ni)
        acc[mi][ni] = __builtin_amdgcn_mfma_f32_16x16x32_bf16(
            afrag[mi], bfrag[ni], acc[mi][ni], 0, 0, 0);
  };

  auto ybody = [&](U5 (&p0)[5], U5 (&p1)[5], U5 (&p2)[5], int y, int dyi, bool last) {
    // B DMA: row y+8 into slot (y+8)&15 (lane-15 read of it this y is the
    // discarded phantom dy=15 column -- benign, R4-proven)
    if (!last) {
      const int yy   = y + 15;
      const int slot = (y + 8) & 15;
      for (int ro = wv; ro < KCLS; ro += 4)
        if (lane < 29)
          glds16(Bb + ((size_t)ro * BPH + yy) * BSTRIDE + lane * 8,
                 ldsB + (ro * 16 + slot) * BSTRIDE);
    }
    const int slotB = (y + PADV - l15) & 15;
    fetchA(p2, dyi, 2);               computeS(p0, slotB, 0);
    fetchA(p0, dyi, 3);               computeS(p1, slotB, 1);
    fetchA(p1, dyi, 4);               computeS(p2, slotB, 2);
    fetchA(p2, dyi, 5);               computeS(p0, slotB, 3);
    fetchA(p0, dyi, 6);               computeS(p1, slotB, 4);
    if (!last) fetchA(p1, dyi + 1, 0); computeS(p2, slotB, 5);
    if (!last) fetchA(p2, dyi + 1, 1); computeS(p0, slotB, 6);
    if (!last) __syncthreads();
  };

  // prologue A fetches for (y0,0) and (y0,1)
  fetchA(b0, 0, 0);
  fetchA(b1, 0, 1);
  __syncthreads();   // drains prologue B DMA

#pragma unroll 1
  for (int k = 0; k < 2; ++k) {
    const int yb = y0 + 3 * k;
    ybody(b0, b1, b2, yb + 0, 0, false);
    ybody(b1, b2, b0, yb + 1, 1, false);
    ybody(b2, b0, b1, yb + 2, 2, false);
#pragma unroll
    for (int mi = 0; mi < 5; ++mi) PA[mi] += 3 * ADW;
  }
  ybody(b0, b1, b2, y0 + 6, 0, true);

  // ---- atomic epilogue: C/D layout col = lane&15, row = quad*4 + reg ----
#pragma unroll
  for (int mi = 0; mi < 5; ++mi)
#pragma unroll
    for (int ni = 0; ni < 5; ++ni) {
      const int mrow = (wm * 5 + mi) * 16 + quad * 4;
      const int ncol = (wn * 5 + ni) * 16 + l15;
#pragma unroll
      for (int r = 0; r < 4; ++r)
        unsafeAtomicAdd(&Cmat[(size_t)(mrow + r) * MD + ncol], acc[mi][ni][r]);
    }
}

// ------------------------------ minred: per-256-cell block min (valid only)
__global__ __launch_bounds__(256)
void minred(const float* __restrict__ Cmat, float* __restrict__ mins) {
  const int c = blockIdx.x * 256 + threadIdx.x;
  const float sf = Cmat[c];
  const int m  = c / MD;
  const int nn = c - m * MD;
  const bool valid = ((m & 15) < TS) && ((nn & 15) < TS);
  __shared__ float red[256];
  red[threadIdx.x] = valid ? sf : 3.4e38f;
  __syncthreads();
  for (int st = 128; st > 0; st >>= 1) {
    if (threadIdx.x < st)
      red[threadIdx.x] = fminf(red[threadIdx.x], red[threadIdx.x + st]);
    __syncthreads();
  }
  if (threadIdx.x == 0) mins[blockIdx.x] = red[0];
}

// ------------------- loss: per-shift fp64, inline global min (100 mins)
__global__ __launch_bounds__(128)
void loss_kernel(const float* __restrict__ Cmat, const float* __restrict__ mins,
                 float* __restrict__ dout) {
  const int s   = blockIdx.x;
  const int dy  = s / TS;
  const int dx  = s - dy * TS;
  const int tid = threadIdx.x;
  __shared__ float fm[128];
  __shared__ double q[100];
  __shared__ double sym[100];
  __shared__ double pi[10], pj[10];
  __shared__ double red[128];

  fm[tid] = (tid < 100) ? mins[tid] : 3.4e38f;
  __syncthreads();
  for (int st = 64; st > 0; st >>= 1) {
    if (tid < st) fm[tid] = fminf(fm[tid], fm[tid + st]);
    __syncthreads();
  }
  const double minv = (double)fm[0];
  __syncthreads();

  if (tid < 100) {
    const int n = tid / 10, o = tid - (tid / 10) * 10;
    const double vv = (double)Cmat[(size_t)(n * 16 + dx) * MD + (o * 16 + dy)];
    q[tid] = vv - minv + LEPS;
  }
  __syncthreads();
  red[tid] = (tid < 100) ? q[tid] : 0.0;
  __syncthreads();
  for (int st = 64; st > 0; st >>= 1) {
    if (tid < st) red[tid] += red[tid + st];
    __syncthreads();
  }
  const double Z = red[0];
  __syncthreads();
  if (tid < 100) {
    const int n = tid / 10, o = tid - (tid / 10) * 10;
    sym[tid] = (q[n * 10 + o] + q[o * 10 + n]) * 0.5 / Z;
  }
  __syncthreads();
  if (tid < 10) {
    double a = 0.0, bsum = 0.0;
    for (int n2 = 0; n2 < 10; ++n2) {
      a    += sym[n2 * 10 + tid];
      bsum += sym[tid * 10 + n2];
    }
    pi[tid] = a;
    pj[tid] = bsum;
  }
  __syncthreads();
  double term = 0.0;
  if (tid < 100) {
    const int n = tid / 10, o = tid - (tid / 10) * 10;
    const double sp = sym[tid];
    term = -sp * (log(sp + LEPS) - log(pi[o] + LEPS) - log(pj[n] + LEPS));
  }
  red[tid] = term;
  __syncthreads();
  for (int st = 64; st > 0; st >>= 1) {
    if (tid < st) red[tid] += red[tid + st];
    __syncthreads();
  }
  if (tid == 0) atomicAdd(dout, (float)(red[0] / (double)(TS * TS)));
}

extern "C" void kernel_launch(void* const* d_in, const int* in_sizes, int n_in,
                              void* d_out, int out_size, void* d_ws, size_t ws_size,
                              hipStream_t stream) {
  const float* xo = (const float*)d_in[0];
  const float* xt = (const float*)d_in[1];
  float* ws       = (float*)d_ws;

  float* Cmat     = ws;                                  // 25600 f32 = 0.1 MB
  float* mins     = Cmat + NCELL;                        // 100 (pad 128)
  unsigned short* bpad = (unsigned short*)(mins + 128);  // 17.8 MB
  uint32_t* apad  = (uint32_t*)(bpad + (size_t)160 * BPH * BSTRIDE);  // 17.2 MB
  float* out      = (float*)d_out;

  hipMemsetAsync(Cmat, 0, (size_t)NCELL * sizeof(float), stream);
  hipMemsetAsync(out, 0, sizeof(float), stream);
  hipLaunchKernelGGL(prep,       dim3(BPREP_BLOCKS + APREP_BLOCKS), dim3(256), 0, stream,
                     xo, xt, bpad, apad);
  hipLaunchKernelGGL(corr_gemm,  dim3(512), dim3(256), 0, stream, apad, bpad, Cmat);
  hipLaunchKernelGGL(minred,     dim3(100), dim3(256), 0, stream, Cmat, mins);
  hipLaunchKernelGGL(loss_kernel,dim3(225), dim3(128), 0, stream, Cmat, mins, out);
}